// Round 1
// baseline (516.318 us; speedup 1.0000x reference)
//
#include <hip/hip_runtime.h>

#define NCLS 100
#define DIM  512
#define EPSV 1e-8f

#define CHUNKS  128      // row chunks
#define SLICES  4        // dim slices of 128
#define SLICE_D 128
#define LBATCH  800      // label staging batch (>= ceil(100000/128)=782)

// ---------------- fused segment-sum + histogram ----------------
// grid = (SLICES, CHUNKS). Block streams a contiguous row range, accumulates
// per-class sums for its 128-dim slice in LDS (XOR-swizzled, conflict-free),
// writes a deterministic partial. Slice-0 blocks also histogram the labels.
__global__ __launch_bounds__(256) void sum_kernel(const float* __restrict__ feat,
                                                  const int* __restrict__ label,
                                                  float* __restrict__ partial,
                                                  int* __restrict__ cnt, int n) {
    __shared__ float acc[NCLS * SLICE_D];   // swizzled slots
    __shared__ int   lab[LBATCH];
    __shared__ int   hcnt[NCLS];

    const int tid = threadIdx.x;
    const int s   = blockIdx.x;             // dim slice
    const int ch  = blockIdx.y;             // row chunk

    for (int i = tid; i < NCLS * SLICE_D; i += 256) acc[i] = 0.0f;
    if (s == 0)
        for (int i = tid; i < NCLS; i += 256) hcnt[i] = 0;

    const int rpc  = (n + CHUNKS - 1) / CHUNKS;
    const int r0   = ch * rpc;
    const int rows = min(rpc, n - r0);      // may be <= 0 on tail chunks
    const int g    = tid >> 5;              // row group 0..7
    const int l    = tid & 31;              // lane within row (covers 4 dims)
    const int swz  = (l >> 3) & 3;          // bank-conflict swizzle
    const float* fbase = feat + (size_t)s * SLICE_D + (size_t)l * 4;

    for (int b0 = 0; b0 < rows; b0 += LBATCH) {
        const int bn = min(LBATCH, rows - b0);
        __syncthreads();
        for (int i = tid; i < bn; i += 256) lab[i] = label[r0 + b0 + i];
        __syncthreads();

        int i = g;
        for (; i + 24 < bn; i += 32) {       // 4 rows in flight per thread
            float4 v[4]; int c[4];
            #pragma unroll
            for (int u = 0; u < 4; ++u) {
                const int r = r0 + b0 + i + 8 * u;
                c[u] = lab[i + 8 * u];
                v[u] = *(const float4*)(fbase + (size_t)r * DIM);
            }
            #pragma unroll
            for (int u = 0; u < 4; ++u) {
                float* a = &acc[c[u] * SLICE_D + l * 4];
                atomicAdd(&a[0 ^ swz], v[u].x);
                atomicAdd(&a[1 ^ swz], v[u].y);
                atomicAdd(&a[2 ^ swz], v[u].z);
                atomicAdd(&a[3 ^ swz], v[u].w);
                if (s == 0 && l == 0) atomicAdd(&hcnt[c[u]], 1);
            }
        }
        for (; i < bn; i += 8) {
            const int c = lab[i];
            float4 v = *(const float4*)(fbase + (size_t)(r0 + b0 + i) * DIM);
            float* a = &acc[c * SLICE_D + l * 4];
            atomicAdd(&a[0 ^ swz], v.x);
            atomicAdd(&a[1 ^ swz], v.y);
            atomicAdd(&a[2 ^ swz], v.z);
            atomicAdd(&a[3 ^ swz], v.w);
            if (s == 0 && l == 0) atomicAdd(&hcnt[c], 1);
        }
    }
    __syncthreads();

    float* dst = partial + ((size_t)ch * SLICES + s) * (NCLS * SLICE_D);
    for (int i = tid; i < NCLS * SLICE_D; i += 256) dst[i] = acc[i];
    if (s == 0)
        for (int i = tid; i < NCLS; i += 256)
            if (hcnt[i]) atomicAdd(&cnt[i], hcnt[i]);
}

// ---------------- reduce partials -> normalized means ----------------
// mhat[c] = mean_c / max(||mean_c||, eps). One block per class.
__global__ __launch_bounds__(256) void finalize_kernel(const float* __restrict__ partial,
                                                       const int* __restrict__ cnt,
                                                       float* __restrict__ mhat) {
    const int c = blockIdx.x;
    const int t = threadIdx.x;
    const float inv = 1.0f / fmaxf((float)cnt[c], 1.0f);

    float m[2];
    #pragma unroll
    for (int h = 0; h < 2; ++h) {
        const int d    = t + 256 * h;
        const int sl   = d >> 7;                 // slice
        const int d7   = d & 127;
        const int lsub = d7 >> 2;
        const int slot = (d7 & ~3) | ((d & 3) ^ ((lsub >> 3) & 3));  // unswizzle
        const float* p = partial + (size_t)sl * (NCLS * SLICE_D)
                                 + (size_t)c * SLICE_D + slot;
        float a = 0.0f;
        #pragma unroll 4
        for (int ch = 0; ch < CHUNKS; ++ch)
            a += p[(size_t)ch * (SLICES * NCLS * SLICE_D)];
        m[h] = a * inv;
    }

    float ss = m[0] * m[0] + m[1] * m[1];
    #pragma unroll
    for (int off = 32; off; off >>= 1) ss += __shfl_down(ss, off, 64);
    __shared__ float red[4];
    if ((t & 63) == 0) red[t >> 6] = ss;
    __syncthreads();
    const float tot = red[0] + red[1] + red[2] + red[3];
    const float q = 1.0f / fmaxf(sqrtf(tot), EPSV);
    mhat[(size_t)c * DIM + t]       = m[0] * q;
    mhat[(size_t)c * DIM + 256 + t] = m[1] * q;
}

// ---------------- cosine: 16 lanes per row, 4 rows per wave ----------------
__global__ __launch_bounds__(256) void cos_kernel(const float* __restrict__ feat,
                                                  const int* __restrict__ label,
                                                  const float* __restrict__ mhat,
                                                  float* __restrict__ out, int n) {
    const int lane = threadIdx.x & 63;
    const int wv   = threadIdx.x >> 6;
    const int cl   = lane >> 4;
    const int t    = lane & 15;

    const int row = blockIdx.x * 16 + wv * 4 + cl;
    const bool ok = row < n;
    const int rr = ok ? row : (n - 1);

    const int c = label[rr];
    const float4* f4 = (const float4*)(feat + (size_t)rr * DIM);
    const float4* m4 = (const float4*)(mhat + (size_t)c  * DIM);

    float4 a[8], b[8];
    #pragma unroll
    for (int j = 0; j < 8; ++j) a[j] = f4[t + 16 * j];
    #pragma unroll
    for (int j = 0; j < 8; ++j) b[j] = m4[t + 16 * j];

    float dot = 0.0f, nf = 0.0f;
    #pragma unroll
    for (int j = 0; j < 8; ++j) {
        dot += a[j].x * b[j].x + a[j].y * b[j].y + a[j].z * b[j].z + a[j].w * b[j].w;
        nf  += a[j].x * a[j].x + a[j].y * a[j].y + a[j].z * a[j].z + a[j].w * a[j].w;
    }

    #pragma unroll
    for (int off = 8; off; off >>= 1) {
        dot += __shfl_xor(dot, off, 64);
        nf  += __shfl_xor(nf,  off, 64);
    }
    if (t == 0 && ok) {
        out[row] = dot / fmaxf(sqrtf(nf), EPSV);
    }
}

extern "C" void kernel_launch(void* const* d_in, const int* in_sizes, int n_in,
                              void* d_out, int out_size, void* d_ws, size_t ws_size,
                              hipStream_t stream) {
    const float* feat  = (const float*)d_in[0];
    const int*   label = (const int*)d_in[1];
    float*       out   = (float*)d_out;
    const int n = in_sizes[0] / DIM;   // 100000

    // ws layout (4 B units):
    // cnt[128] | mhat[100*512] | partial[CHUNKS*SLICES*NCLS*SLICE_D]  (~26 MB)
    int*   cnt     = (int*)d_ws;
    float* mhat    = (float*)(cnt + 128);
    float* partial = mhat + NCLS * DIM;

    // only cnt needs zeroing (ws is poisoned 0xAA before every call);
    // partial and mhat are fully written before being read.
    hipMemsetAsync(cnt, 0, 128 * sizeof(int), stream);

    dim3 sg(SLICES, CHUNKS);           // 512 blocks, 2 per CU
    sum_kernel<<<sg, 256, 0, stream>>>(feat, label, partial, cnt, n);
    finalize_kernel<<<NCLS, 256, 0, stream>>>(partial, cnt, mhat);
    cos_kernel<<<(n + 15) / 16, 256, 0, stream>>>(feat, label, mhat, out, n);
}

// Round 2
// 401.334 us; speedup vs baseline: 1.2865x; 1.2865x over previous
//
#include <hip/hip_runtime.h>

#define NCLS 100
#define DIM  512
#define EPSV 1e-8f

#define DSPL   4      // dim splits of 128 dims
#define CH     192    // row chunks -> 768 one-wave blocks = 3 blocks/CU at 51.2 KB LDS
#define BATCH  16

// ---------------- histogram of labels ----------------
__global__ __launch_bounds__(256) void hist_kernel(const int* __restrict__ label,
                                                   int* __restrict__ cnt, int n) {
    __shared__ int h[NCLS];
    for (int i = threadIdx.x; i < NCLS; i += 256) h[i] = 0;
    __syncthreads();
    for (int i = blockIdx.x * 256 + threadIdx.x; i < n; i += gridDim.x * 256)
        atomicAdd(&h[label[i]], 1);
    __syncthreads();
    for (int i = threadIdx.x; i < NCLS; i += 256) {
        int v = h[i];
        if (v) atomicAdd(&cnt[i], v);
    }
}

// ---------------- segment-sum: wave-private LDS, NO atomics ----------------
// Block = 1 wave. Block (ds, ch) owns dims [ds*128, (ds+1)*128) of row chunk ch.
// acc[class][128] lives in LDS and is private to the wave -> plain RMW.
// Rows go in batches of 16: global loads issued 16-deep; duplicate classes
// within the batch are merged in registers (classes are wave-uniform scalars,
// so the compares are scalar branches, rarely taken); then a read-all /
// write-all RMW window touches pairwise-distinct LDS addresses. Same-wave DS
// ops complete in order, so cross-batch RAW is safe without barriers.
__global__ __launch_bounds__(64) void sum_kernel(const float* __restrict__ feat,
                                                 const int* __restrict__ label,
                                                 float* __restrict__ partial, int n) {
    __shared__ float acc[NCLS * 128];
    const int lane = threadIdx.x;          // 0..63, covers 128 dims as float2
    const int ds   = blockIdx.x;           // 0..3
    const int ch   = blockIdx.y;           // 0..CH-1

    #pragma unroll 4
    for (int i = lane; i < NCLS * 128; i += 64) acc[i] = 0.0f;

    const int rpc  = (n + CH - 1) / CH;    // 521
    const int r0   = ch * rpc;
    const int rows = min(rpc, n - r0);
    const float* fb = feat + (size_t)ds * 128 + (size_t)lane * 2;
    float2* accv = (float2*)acc;           // accv[c*64 + lane]

    int r = 0;
    for (; r + BATCH <= rows; r += BATCH) {
        float2 v[BATCH];
        int    c[BATCH];
        #pragma unroll
        for (int k = 0; k < BATCH; ++k) {
            c[k] = label[r0 + r + k];                              // uniform -> SGPR
            v[k] = *(const float2*)(fb + (size_t)(r0 + r + k) * DIM);
        }
        // merge duplicate classes (exact: all pairs within the RMW window)
        #pragma unroll
        for (int i = 0; i < BATCH; ++i) {
            #pragma unroll
            for (int j = i + 1; j < BATCH; ++j) {
                if (c[j] == c[i]) { v[i].x += v[j].x; v[i].y += v[j].y; c[j] = -1; }
            }
        }
        // read-all / write-all RMW window (addresses pairwise distinct)
        float2 t[BATCH];
        #pragma unroll
        for (int k = 0; k < BATCH; ++k)
            if (c[k] >= 0) t[k] = accv[c[k] * 64 + lane];
        #pragma unroll
        for (int k = 0; k < BATCH; ++k)
            if (c[k] >= 0) {
                t[k].x += v[k].x; t[k].y += v[k].y;
                accv[c[k] * 64 + lane] = t[k];
            }
    }
    for (; r < rows; ++r) {                // tail: sequential RMW, always exact
        const int c0 = label[r0 + r];
        float2 v = *(const float2*)(fb + (size_t)(r0 + r) * DIM);
        float2 t = accv[c0 * 64 + lane];
        t.x += v.x; t.y += v.y;
        accv[c0 * 64 + lane] = t;
    }

    // deterministic partial: [ch][ds][class][128]
    float* dst = partial + ((size_t)ch * DSPL + ds) * (NCLS * 128);
    #pragma unroll 4
    for (int i = lane; i < NCLS * 128; i += 64) dst[i] = acc[i];
}

// ---------------- reduce partials -> normalized means ----------------
__global__ __launch_bounds__(512) void finalize_kernel(const float* __restrict__ partial,
                                                       const int* __restrict__ cnt,
                                                       float* __restrict__ mhat) {
    const int c = blockIdx.x;
    const int t = threadIdx.x;             // dim 0..511
    const int ds  = t >> 7;
    const int off = t & 127;
    const float* p = partial + ((size_t)ds * NCLS + c) * 128 + off;
    const size_t stride = (size_t)DSPL * NCLS * 128;

    float a0 = 0.f, a1 = 0.f, a2 = 0.f, a3 = 0.f;
    for (int ch = 0; ch < CH; ch += 4) {
        a0 += p[(size_t)(ch + 0) * stride];
        a1 += p[(size_t)(ch + 1) * stride];
        a2 += p[(size_t)(ch + 2) * stride];
        a3 += p[(size_t)(ch + 3) * stride];
    }
    const float m = ((a0 + a1) + (a2 + a3)) / fmaxf((float)cnt[c], 1.0f);

    float ss = m * m;
    #pragma unroll
    for (int o = 32; o; o >>= 1) ss += __shfl_down(ss, o, 64);
    __shared__ float red[8];
    if ((t & 63) == 0) red[t >> 6] = ss;
    __syncthreads();
    float tot = 0.f;
    #pragma unroll
    for (int k = 0; k < 8; ++k) tot += red[k];
    const float q = 1.0f / fmaxf(sqrtf(tot), EPSV);
    mhat[(size_t)c * DIM + t] = m * q;
}

// ---------------- cosine: 16 lanes per row, 4 rows per wave ----------------
__global__ __launch_bounds__(256) void cos_kernel(const float* __restrict__ feat,
                                                  const int* __restrict__ label,
                                                  const float* __restrict__ mhat,
                                                  float* __restrict__ out, int n) {
    const int lane = threadIdx.x & 63;
    const int wv   = threadIdx.x >> 6;
    const int cl   = lane >> 4;
    const int t    = lane & 15;

    const int row = blockIdx.x * 16 + wv * 4 + cl;
    const bool ok = row < n;
    const int rr = ok ? row : (n - 1);

    const int c = label[rr];
    const float4* f4 = (const float4*)(feat + (size_t)rr * DIM);
    const float4* m4 = (const float4*)(mhat + (size_t)c  * DIM);

    float4 a[8], b[8];
    #pragma unroll
    for (int j = 0; j < 8; ++j) a[j] = f4[t + 16 * j];
    #pragma unroll
    for (int j = 0; j < 8; ++j) b[j] = m4[t + 16 * j];

    float dot = 0.0f, nf = 0.0f;
    #pragma unroll
    for (int j = 0; j < 8; ++j) {
        dot += a[j].x * b[j].x + a[j].y * b[j].y + a[j].z * b[j].z + a[j].w * b[j].w;
        nf  += a[j].x * a[j].x + a[j].y * a[j].y + a[j].z * a[j].z + a[j].w * a[j].w;
    }

    #pragma unroll
    for (int off = 8; off; off >>= 1) {
        dot += __shfl_xor(dot, off, 64);
        nf  += __shfl_xor(nf,  off, 64);
    }
    if (t == 0 && ok) {
        out[row] = dot / fmaxf(sqrtf(nf), EPSV);
    }
}

extern "C" void kernel_launch(void* const* d_in, const int* in_sizes, int n_in,
                              void* d_out, int out_size, void* d_ws, size_t ws_size,
                              hipStream_t stream) {
    const float* feat  = (const float*)d_in[0];
    const int*   label = (const int*)d_in[1];
    float*       out   = (float*)d_out;
    const int n = in_sizes[0] / DIM;   // 100000

    // ws layout (4 B units):
    // cnt[128] | mhat[100*512] | partial[CH*DSPL*NCLS*128]  (~39.3 MB)
    int*   cnt     = (int*)d_ws;
    float* mhat    = (float*)(cnt + 128);
    float* partial = mhat + NCLS * DIM;

    hipMemsetAsync(cnt, 0, 128 * sizeof(int), stream);

    hist_kernel<<<160, 256, 0, stream>>>(label, cnt, n);

    dim3 sg(DSPL, CH);                 // 768 one-wave blocks
    sum_kernel<<<sg, 64, 0, stream>>>(feat, label, partial, n);

    finalize_kernel<<<NCLS, 512, 0, stream>>>(partial, cnt, mhat);

    cos_kernel<<<(n + 15) / 16, 256, 0, stream>>>(feat, label, mhat, out, n);
}

// Round 3
// 354.486 us; speedup vs baseline: 1.4565x; 1.1322x over previous
//
#include <hip/hip_runtime.h>

#define NCLS 100
#define DIM  512
#define EPSV 1e-8f

#define DSPL   8      // dim splits of 64 dims; lane owns 1 float
#define CH     192    // row chunks -> 1536 one-wave blocks = 6 blocks/CU (25.9 KB LDS)
#define BATCH  32
#define SUBG   8      // RMW sub-group size (merge window)

// ---------------- histogram of labels ----------------
__global__ __launch_bounds__(256) void hist_kernel(const int* __restrict__ label,
                                                   int* __restrict__ cnt, int n) {
    __shared__ int h[NCLS];
    for (int i = threadIdx.x; i < NCLS; i += 256) h[i] = 0;
    __syncthreads();
    for (int i = blockIdx.x * 256 + threadIdx.x; i < n; i += gridDim.x * 256)
        atomicAdd(&h[label[i]], 1);
    __syncthreads();
    for (int i = threadIdx.x; i < NCLS; i += 256) {
        int v = h[i];
        if (v) atomicAdd(&cnt[i], v);
    }
}

// ---------------- segment-sum: wave-private LDS, no atomics, pipelined ----------------
// Block = 1 wave, owns dims [ds*64, ds*64+64) of row chunk ch.
// acc[class][64] is wave-private -> plain ds RMW. Classes 0..99 + trash slot 100.
// Batches of 32 rows, double-buffered: batch b+1's loads are issued before
// processing batch b, so the compiler's counted vmcnt overlaps HBM latency
// with merge+RMW. Within each 8-row RMW window, duplicate classes are merged
// branchlessly (dup -> trash slot). Across windows, correctness comes from
// in-order DS ops + the compiler's inability to reorder may-aliasing LDS ops.
__global__ __launch_bounds__(64) void sum_kernel(const float* __restrict__ feat,
                                                 const int* __restrict__ label,
                                                 float* __restrict__ partial, int n) {
    __shared__ float acc[(NCLS + 1) * 64];
    const int lane = threadIdx.x;
    const int ds   = blockIdx.x;
    const int ch   = blockIdx.y;

    float4* a4 = (float4*)acc;
    #pragma unroll
    for (int i = lane; i < (NCLS + 1) * 16; i += 64)
        a4[i] = make_float4(0.f, 0.f, 0.f, 0.f);

    const int rpc  = (n + CH - 1) / CH;
    const int r0   = ch * rpc;
    const int rows = min(rpc, n - r0);
    const float* fb = feat + ds * 64 + lane;

    float vA[BATCH], vB[BATCH];
    int mylA = 0, mylB = 0;

    auto loadA = [&](int rb) {
        mylA = label[r0 + rb + (lane & (BATCH - 1))];
        #pragma unroll
        for (int k = 0; k < BATCH; ++k)
            vA[k] = fb[(size_t)(r0 + rb + k) * DIM];
    };
    auto loadB = [&](int rb) {
        mylB = label[r0 + rb + (lane & (BATCH - 1))];
        #pragma unroll
        for (int k = 0; k < BATCH; ++k)
            vB[k] = fb[(size_t)(r0 + rb + k) * DIM];
    };
    auto proc = [&](int myl, float (&v)[BATCH]) {
        int c[BATCH];
        #pragma unroll
        for (int k = 0; k < BATCH; ++k) c[k] = __shfl(myl, k, 64);
        #pragma unroll
        for (int g = 0; g < BATCH; g += SUBG) {
            // branchless all-pairs merge within the RMW window
            #pragma unroll
            for (int i = 0; i < SUBG; ++i) {
                #pragma unroll
                for (int j = i + 1; j < SUBG; ++j) {
                    const bool eq = (c[g + j] == c[g + i]);
                    v[g + i] += eq ? v[g + j] : 0.0f;
                    c[g + j] = eq ? NCLS : c[g + j];   // dup -> trash slot
                }
            }
            // read-all / write-all: addresses pairwise distinct within window
            float t[SUBG];
            #pragma unroll
            for (int k = 0; k < SUBG; ++k) t[k] = acc[c[g + k] * 64 + lane];
            #pragma unroll
            for (int k = 0; k < SUBG; ++k) acc[c[g + k] * 64 + lane] = t[k] + v[g + k];
        }
    };

    const int nb = rows / BATCH;
    if (nb > 0) {
        loadA(0);
        for (int ib = 0; ib + 1 < nb; ++ib) {
            if (ib & 1) { loadA((ib + 1) * BATCH); proc(mylB, vB); }
            else        { loadB((ib + 1) * BATCH); proc(mylA, vA); }
        }
        if ((nb - 1) & 1) proc(mylB, vB); else proc(mylA, vA);
    }
    for (int r = nb * BATCH; r < rows; ++r) {   // tail: sequential RMW, alias-safe
        const int c0 = label[r0 + r];
        acc[c0 * 64 + lane] += fb[(size_t)(r0 + r) * DIM];
    }

    // deterministic partial: [ch][ds][class][64] (trash slot not written)
    float4* dst = (float4*)(partial + ((size_t)ch * DSPL + ds) * (NCLS * 64));
    #pragma unroll
    for (int i = lane; i < NCLS * 16; i += 64) dst[i] = a4[i];
}

// ---------------- reduce partials -> normalized means ----------------
__global__ __launch_bounds__(512) void finalize_kernel(const float* __restrict__ partial,
                                                       const int* __restrict__ cnt,
                                                       float* __restrict__ mhat) {
    const int c = blockIdx.x;
    const int t = threadIdx.x;             // dim 0..511
    const int ds  = t >> 6;
    const int off = t & 63;
    const float* p = partial + (size_t)ds * (NCLS * 64) + (size_t)c * 64 + off;
    const size_t stride = (size_t)DSPL * NCLS * 64;

    float a0 = 0.f, a1 = 0.f, a2 = 0.f, a3 = 0.f;
    for (int ch = 0; ch < CH; ch += 4) {
        a0 += p[(size_t)(ch + 0) * stride];
        a1 += p[(size_t)(ch + 1) * stride];
        a2 += p[(size_t)(ch + 2) * stride];
        a3 += p[(size_t)(ch + 3) * stride];
    }
    const float m = ((a0 + a1) + (a2 + a3)) / fmaxf((float)cnt[c], 1.0f);

    float ss = m * m;
    #pragma unroll
    for (int o = 32; o; o >>= 1) ss += __shfl_down(ss, o, 64);
    __shared__ float red[8];
    if ((t & 63) == 0) red[t >> 6] = ss;
    __syncthreads();
    float tot = 0.f;
    #pragma unroll
    for (int k = 0; k < 8; ++k) tot += red[k];
    const float q = 1.0f / fmaxf(sqrtf(tot), EPSV);
    mhat[(size_t)c * DIM + t] = m * q;
}

// ---------------- cosine: 16 lanes per row, 4 rows per wave ----------------
__global__ __launch_bounds__(256) void cos_kernel(const float* __restrict__ feat,
                                                  const int* __restrict__ label,
                                                  const float* __restrict__ mhat,
                                                  float* __restrict__ out, int n) {
    const int lane = threadIdx.x & 63;
    const int wv   = threadIdx.x >> 6;
    const int cl   = lane >> 4;
    const int t    = lane & 15;

    const int row = blockIdx.x * 16 + wv * 4 + cl;
    const bool ok = row < n;
    const int rr = ok ? row : (n - 1);

    const int c = label[rr];
    const float4* f4 = (const float4*)(feat + (size_t)rr * DIM);
    const float4* m4 = (const float4*)(mhat + (size_t)c  * DIM);

    float4 a[8], b[8];
    #pragma unroll
    for (int j = 0; j < 8; ++j) a[j] = f4[t + 16 * j];
    #pragma unroll
    for (int j = 0; j < 8; ++j) b[j] = m4[t + 16 * j];

    float dot = 0.0f, nf = 0.0f;
    #pragma unroll
    for (int j = 0; j < 8; ++j) {
        dot += a[j].x * b[j].x + a[j].y * b[j].y + a[j].z * b[j].z + a[j].w * b[j].w;
        nf  += a[j].x * a[j].x + a[j].y * a[j].y + a[j].z * a[j].z + a[j].w * a[j].w;
    }

    #pragma unroll
    for (int off = 8; off; off >>= 1) {
        dot += __shfl_xor(dot, off, 64);
        nf  += __shfl_xor(nf,  off, 64);
    }
    if (t == 0 && ok) {
        out[row] = dot / fmaxf(sqrtf(nf), EPSV);
    }
}

extern "C" void kernel_launch(void* const* d_in, const int* in_sizes, int n_in,
                              void* d_out, int out_size, void* d_ws, size_t ws_size,
                              hipStream_t stream) {
    const float* feat  = (const float*)d_in[0];
    const int*   label = (const int*)d_in[1];
    float*       out   = (float*)d_out;
    const int n = in_sizes[0] / DIM;   // 100000

    // ws layout (4 B units):
    // cnt[128] | mhat[100*512] | partial[CH*DSPL*NCLS*64]  (~39.3 MB)
    int*   cnt     = (int*)d_ws;
    float* mhat    = (float*)(cnt + 128);
    float* partial = mhat + NCLS * DIM;

    hipMemsetAsync(cnt, 0, 128 * sizeof(int), stream);

    hist_kernel<<<160, 256, 0, stream>>>(label, cnt, n);

    dim3 sg(DSPL, CH);                 // 1536 one-wave blocks, 6/CU
    sum_kernel<<<sg, 64, 0, stream>>>(feat, label, partial, n);

    finalize_kernel<<<NCLS, 512, 0, stream>>>(partial, cnt, mhat);

    cos_kernel<<<(n + 15) / 16, 256, 0, stream>>>(feat, label, mhat, out, n);
}

// Round 4
// 332.236 us; speedup vs baseline: 1.5541x; 1.0670x over previous
//
#include <hip/hip_runtime.h>

#define NCLS 100
#define DIM  512
#define EPSV 1e-8f

#define DSPL 8            // dim splits of 64; lane owns 1 float
#define CH   192          // row chunks -> grid 8x192 = 1536 blocks = 6/CU (25.4+0.4 KB LDS)
#define NW   4            // waves per block
#define SCALE    262144.0f          // 2^18 fixed-point scale
#define INVSCALE (1.0f / 262144.0f)

// ---------------- segment-sum: fixed-point int LDS atomics, block-shared ----------------
// Block (ds, ch) = 256 threads (4 waves) handles row chunk ch, dims [ds*64, ds*64+64).
// acc[class][64] is int (v * 2^18, rounded) shared by the whole block via native
// ds_add_u32 atomics (no CAS, no privacy constraint -> 24 waves/CU of TLP).
// Per-chunk partial magnitudes are tiny (~5 rows/class/chunk), so 2^18 scaling has
// ~80x overflow headroom and ~2e-6/element quantization error (cosine delta ~1e-5).
// ds==0 blocks also produce deterministic per-chunk label counts (no global atomics,
// no memset needed anywhere).
__global__ __launch_bounds__(256) void sum_kernel(const float* __restrict__ feat,
                                                  const int* __restrict__ label,
                                                  int* __restrict__ partial,
                                                  int* __restrict__ cntp, int n) {
    __shared__ int acc[NCLS * 64];
    __shared__ int hcnt[NCLS];
    const int tid = threadIdx.x;
    const int ds  = blockIdx.x;
    const int ch  = blockIdx.y;

    for (int i = tid; i < NCLS * 64; i += 256) acc[i] = 0;
    if (ds == 0)
        for (int i = tid; i < NCLS; i += 256) hcnt[i] = 0;
    __syncthreads();

    const int rpc  = (n + CH - 1) / CH;
    const int r0   = ch * rpc;
    const int rows = max(0, min(rpc, n - r0));
    const int w    = tid >> 6;
    const int lane = tid & 63;
    const int lo   = (rows * w) / NW;
    const int hi   = (rows * (w + 1)) / NW;
    const float* fb = feat + ds * 64 + lane;

    int r = lo;
    for (; r + 8 <= hi; r += 8) {
        // 8 coalesced 256B row-slice loads in flight + 1 label dword (lanes 0-7)
        float v[8];
        #pragma unroll
        for (int k = 0; k < 8; ++k) v[k] = fb[(size_t)(r0 + r + k) * DIM];
        const int myl = label[r0 + r + (lane & 7)];
        int c[8];
        #pragma unroll
        for (int k = 0; k < 8; ++k) c[k] = __shfl(myl, k, 64);   // readlane -> SGPR

        #pragma unroll
        for (int k = 0; k < 8; ++k)
            atomicAdd(&acc[c[k] * 64 + lane], __float2int_rn(v[k] * SCALE));
        if (ds == 0 && lane == 0) {
            #pragma unroll
            for (int k = 0; k < 8; ++k) atomicAdd(&hcnt[c[k]], 1);
        }
    }
    for (; r < hi; ++r) {
        const float v = fb[(size_t)(r0 + r) * DIM];
        const int   c = label[r0 + r];
        atomicAdd(&acc[c * 64 + lane], __float2int_rn(v * SCALE));
        if (ds == 0 && lane == 0) atomicAdd(&hcnt[c], 1);
    }
    __syncthreads();

    // deterministic partial: [ch][ds][class][64] ints
    int4* d4 = (int4*)(partial + ((size_t)ch * DSPL + ds) * (NCLS * 64));
    const int4* s4 = (const int4*)acc;
    for (int i = tid; i < NCLS * 16; i += 256) d4[i] = s4[i];
    if (ds == 0)
        for (int i = tid; i < NCLS; i += 256) cntp[ch * 128 + i] = hcnt[i];
}

// ---------------- reduce partials -> normalized means ----------------
// mhat[c] = mean_c / max(||mean_c||, eps). One block per class, thread t = dim t.
__global__ __launch_bounds__(512) void finalize_kernel(const int* __restrict__ partial,
                                                       const int* __restrict__ cntp,
                                                       float* __restrict__ mhat) {
    const int c = blockIdx.x;
    const int t = threadIdx.x;
    __shared__ int   csh[8];
    __shared__ float red[8];
    __shared__ float invsh;

    // count = sum over chunks (exact int)
    int pc = 0;
    for (int ch = t; ch < CH; ch += 512) pc += cntp[ch * 128 + c];
    #pragma unroll
    for (int o = 32; o; o >>= 1) pc += __shfl_down(pc, o, 64);
    if ((t & 63) == 0) csh[t >> 6] = pc;
    __syncthreads();
    if (t == 0) {
        int tot = 0;
        #pragma unroll
        for (int k = 0; k < 8; ++k) tot += csh[k];
        invsh = INVSCALE / fmaxf((float)tot, 1.0f);
    }
    __syncthreads();
    const float inv = invsh;

    // dim t = (ds = t>>6, off = t&63); sum 192 chunk partials (exact in int64)
    const int ds  = t >> 6;
    const int off = t & 63;
    const int* p = partial + ((size_t)ds * NCLS + c) * 64 + off;
    const size_t stride = (size_t)DSPL * NCLS * 64;
    long long a0 = 0, a1 = 0, a2 = 0, a3 = 0;
    for (int ch = 0; ch < CH; ch += 4) {
        a0 += p[(size_t)(ch + 0) * stride];
        a1 += p[(size_t)(ch + 1) * stride];
        a2 += p[(size_t)(ch + 2) * stride];
        a3 += p[(size_t)(ch + 3) * stride];
    }
    const float m = (float)((a0 + a1) + (a2 + a3)) * inv;

    float ss = m * m;
    #pragma unroll
    for (int o = 32; o; o >>= 1) ss += __shfl_down(ss, o, 64);
    if ((t & 63) == 0) red[t >> 6] = ss;
    __syncthreads();
    float tot = 0.f;
    #pragma unroll
    for (int k = 0; k < 8; ++k) tot += red[k];
    const float q = 1.0f / fmaxf(sqrtf(tot), EPSV);
    mhat[(size_t)c * DIM + t] = m * q;
}

// ---------------- cosine: 16 lanes per row, 4 rows per wave ----------------
__global__ __launch_bounds__(256) void cos_kernel(const float* __restrict__ feat,
                                                  const int* __restrict__ label,
                                                  const float* __restrict__ mhat,
                                                  float* __restrict__ out, int n) {
    const int lane = threadIdx.x & 63;
    const int wv   = threadIdx.x >> 6;
    const int cl   = lane >> 4;
    const int t    = lane & 15;

    const int row = blockIdx.x * 16 + wv * 4 + cl;
    const bool ok = row < n;
    const int rr = ok ? row : (n - 1);

    const int c = label[rr];
    const float4* f4 = (const float4*)(feat + (size_t)rr * DIM);
    const float4* m4 = (const float4*)(mhat + (size_t)c  * DIM);

    float4 a[8], b[8];
    #pragma unroll
    for (int j = 0; j < 8; ++j) a[j] = f4[t + 16 * j];
    #pragma unroll
    for (int j = 0; j < 8; ++j) b[j] = m4[t + 16 * j];

    float dot = 0.0f, nf = 0.0f;
    #pragma unroll
    for (int j = 0; j < 8; ++j) {
        dot += a[j].x * b[j].x + a[j].y * b[j].y + a[j].z * b[j].z + a[j].w * b[j].w;
        nf  += a[j].x * a[j].x + a[j].y * a[j].y + a[j].z * a[j].z + a[j].w * a[j].w;
    }

    #pragma unroll
    for (int off = 8; off; off >>= 1) {
        dot += __shfl_xor(dot, off, 64);
        nf  += __shfl_xor(nf,  off, 64);
    }
    if (t == 0 && ok) {
        out[row] = dot / fmaxf(sqrtf(nf), EPSV);
    }
}

extern "C" void kernel_launch(void* const* d_in, const int* in_sizes, int n_in,
                              void* d_out, int out_size, void* d_ws, size_t ws_size,
                              hipStream_t stream) {
    const float* feat  = (const float*)d_in[0];
    const int*   label = (const int*)d_in[1];
    float*       out   = (float*)d_out;
    const int n = in_sizes[0] / DIM;   // 100000

    // ws layout (4 B units):
    // mhat[100*512] | cntp[CH*128] | partial[CH*DSPL*NCLS*64] ints (~39.3 MB)
    // Everything is fully written before being read -> no memset needed at all.
    float* mhat    = (float*)d_ws;
    int*   cntp    = (int*)(mhat + NCLS * DIM);
    int*   partial = cntp + CH * 128;

    dim3 sg(DSPL, CH);                 // 1536 blocks x 256 threads = 6 blocks/CU
    sum_kernel<<<sg, 256, 0, stream>>>(feat, label, partial, cntp, n);

    finalize_kernel<<<NCLS, 512, 0, stream>>>(partial, cntp, mhat);

    cos_kernel<<<(n + 15) / 16, 256, 0, stream>>>(feat, label, mhat, out, n);
}